// Round 1
// baseline (1774.258 us; speedup 1.0000x reference)
//
#include <hip/hip_runtime.h>

// DecoderLSTM: B=4096, T=128 (127 steps), H=128, 4H=512, V=30, E=256.
// Key algebraic simplification: x@W_ih.T has only V=30 distinct rows ->
// precompute Xproj[30][512] = emb@W_ih.T + b_ih + b_hh once.
// Batch rows are independent -> 256 blocks x 16 rows, whole recurrence in one kernel.

namespace {
constexpr int Bn = 4096, Tn = 128, Vn = 30, En = 256, Hn = 128, Gn = 512;
// ws float-offset layout (needs (80912+3840)*4 = ~339 KB of ws)
constexpr int WS_LOSS  = 0;
constexpr int WS_MASK  = 1;
constexpr int WS_XPROJ = 16;                  // 30*512 = 15360 floats
constexpr int WS_WT    = WS_XPROJ + Vn * Gn;  // W_hh^T [128][512] = 65536 floats
constexpr int WS_WLT   = WS_WT + Gn * Hn;     // W_lin^T [128][30] = 3840 floats
}

__device__ __forceinline__ float fexp2(float x) { return __builtin_amdgcn_exp2f(x); }
__device__ __forceinline__ float frcp(float x)  { return __builtin_amdgcn_rcpf(x); }
__device__ __forceinline__ float sigf(float x)  { return frcp(1.f + fexp2(x * -1.44269504f)); }
__device__ __forceinline__ float tanh_(float x) { return 1.f - 2.f * frcp(fexp2(x * 2.88539008f) + 1.f); }

// K_tlin (1 x 256): zero accumulators + transpose W_lin -> WlinT[k][v]
__global__ void k_tlin(const float* __restrict__ W_lin, float* __restrict__ ws) {
  if (threadIdx.x < 2) ws[threadIdx.x] = 0.f;  // WS_LOSS, WS_MASK
  for (int idx = threadIdx.x; idx < Hn * Vn; idx += 256) {
    int k = idx / Vn, v = idx - k * Vn;
    ws[WS_WLT + idx] = W_lin[v * Hn + k];
  }
}

// K_xproj (60 x 256): Xproj[v][j] = dot(emb[v], W_ih[j]) + b_ih[j] + b_hh[j]
__global__ void k_xproj(const float* __restrict__ emb, const float* __restrict__ W_ih,
                        const float* __restrict__ b_ih, const float* __restrict__ b_hh,
                        float* __restrict__ ws) {
  __shared__ __align__(16) float es[En];
  int v = blockIdx.x >> 1;
  int j = ((blockIdx.x & 1) << 8) + threadIdx.x;
  es[threadIdx.x] = emb[v * En + threadIdx.x];
  __syncthreads();
  float a = b_ih[j] + b_hh[j];
  const float* wr = W_ih + j * En;
#pragma unroll 4
  for (int e = 0; e < En; e += 4) {
    float4 w = *(const float4*)(wr + e);
    float4 x = *(const float4*)(es + e);
    a += x.x * w.x + x.y * w.y + x.z * w.z + x.w * w.w;
  }
  ws[WS_XPROJ + v * Gn + j] = a;
}

// K_twhh (64 x 256): WT[k][j] = W_hh[j][k]  (coalesced writes)
__global__ void k_twhh(const float* __restrict__ W_hh, float* __restrict__ ws) {
  int idx = blockIdx.x * 1024 + threadIdx.x;
  float* WT = ws + WS_WT;
#pragma unroll
  for (int i = 0; i < 4; ++i, idx += 256) {
    int k = idx >> 9, j = idx & 511;
    WT[idx] = W_hh[j * Hn + k];
  }
}

// K_mask (128 x 256): ws[WS_MASK] = sum(mask_Y)
__global__ void k_mask(const float* __restrict__ m, float* __restrict__ ws) {
  float s = 0.f;
  for (int i = blockIdx.x * 256 + threadIdx.x; i < Bn * Tn; i += 128 * 256) s += m[i];
#pragma unroll
  for (int off = 32; off > 0; off >>= 1) s += __shfl_down(s, off, 64);
  __shared__ float r[4];
  int lane = threadIdx.x & 63, w = threadIdx.x >> 6;
  if (lane == 0) r[w] = s;
  __syncthreads();
  if (threadIdx.x == 0) atomicAdd(ws + WS_MASK, r[0] + r[1] + r[2] + r[3]);
}

// K_main (256 x 512): 16 batch rows per block, all 127 steps.
// Thread roles per step:
//   gates:    tid -> (jp = tid&255 -> j0=2*jp, half = tid>>8 -> rows half*8..+7)
//   pointwise: tid -> k = tid&127, rows {p*4 + (tid>>7)}, c state in registers
//   logits:   tid<480 -> (row = tid/30, v = tid%30)
//   softmax:  tid<16  -> one row each, CE accumulated in register
__global__ __launch_bounds__(512) void k_main(
    const int* __restrict__ inpt, const float* __restrict__ h0,
    const float* __restrict__ c0, const float* __restrict__ maskY,
    const float* __restrict__ b_lin, float* __restrict__ ws) {
  __shared__ __align__(16) float hT[Hn][20];     // h^T, pad 16->20 (16B-aligned b128 rows)
  __shared__ __align__(16) float gates[16][Gn];  // [row][512]
  __shared__ float logits[16][33];               // pad 33: conflict-free leader scans
  __shared__ int   tok[16][Tn];
  __shared__ float red[16];

  const float* Xp = ws + WS_XPROJ;
  const float* WT = ws + WS_WT;
  const float* WL = ws + WS_WLT;

  const int tid  = threadIdx.x;
  const int row0 = blockIdx.x * 16;

  for (int idx = tid; idx < 16 * Tn; idx += 512) {
    int r = idx >> 7, t = idx & 127;
    tok[r][t] = inpt[(row0 + r) * Tn + t];
  }
  for (int idx = tid; idx < 16 * Hn; idx += 512) {
    int r = idx >> 7, k = idx & 127;
    hT[k][r] = h0[(row0 + r) * Hn + k];
  }
  float creg[4];
  {
    int k = tid & 127, rb = tid >> 7;
#pragma unroll
    for (int p = 0; p < 4; ++p) creg[p] = c0[(row0 + p * 4 + rb) * Hn + k];
  }
  const int jp = tid & 255, half = tid >> 8;
  const int j0 = jp * 2, rbase = half * 8;
  const int lrow = tid / 30, lv = tid - lrow * 30;
  const bool lact = tid < 480;
  const float blin = lact ? b_lin[lv] : 0.f;
  float ce_acc = 0.f;
  __syncthreads();

  for (int t = 0; t < Tn - 1; ++t) {
    // ---- gates: acc[r][0:2] = Xproj[tok[r][t]][j0:j0+2] + h[r] @ WT[:, j0:j0+2]
    float2 acc[8];
#pragma unroll
    for (int r = 0; r < 8; ++r) {
      int tk = tok[rbase + r][t];
      acc[r] = *(const float2*)(Xp + tk * Gn + j0);
    }
#pragma unroll 4
    for (int k = 0; k < Hn; ++k) {
      float2 w  = *(const float2*)(WT + (k << 9) + j0);      // coalesced, L2-hot
      float4 ha = *(const float4*)&hT[k][rbase];             // LDS broadcast
      float4 hb = *(const float4*)&hT[k][rbase + 4];
      acc[0].x += ha.x * w.x; acc[0].y += ha.x * w.y;
      acc[1].x += ha.y * w.x; acc[1].y += ha.y * w.y;
      acc[2].x += ha.z * w.x; acc[2].y += ha.z * w.y;
      acc[3].x += ha.w * w.x; acc[3].y += ha.w * w.y;
      acc[4].x += hb.x * w.x; acc[4].y += hb.x * w.y;
      acc[5].x += hb.y * w.x; acc[5].y += hb.y * w.y;
      acc[6].x += hb.z * w.x; acc[6].y += hb.z * w.y;
      acc[7].x += hb.w * w.x; acc[7].y += hb.w * w.y;
    }
#pragma unroll
    for (int r = 0; r < 8; ++r)
      *(float2*)&gates[rbase + r][j0] = acc[r];
    __syncthreads();

    // ---- pointwise LSTM cell (c in registers, h2 -> hT)
    {
      int k = tid & 127, rb = tid >> 7;
#pragma unroll
      for (int p = 0; p < 4; ++p) {
        int r = p * 4 + rb;
        float gi = gates[r][k],          gf = gates[r][Hn + k];
        float gg = gates[r][2 * Hn + k], go = gates[r][3 * Hn + k];
        float c2 = sigf(gf) * creg[p] + sigf(gi) * tanh_(gg);
        float h2 = sigf(go) * tanh_(c2);
        creg[p] = c2;
        hT[k][r] = h2;
      }
    }
    __syncthreads();

    // ---- logits: 16 rows x 30 vocab
    if (lact) {
      float a = blin;
#pragma unroll 4
      for (int k = 0; k < Hn; ++k)
        a += hT[k][lrow] * WL[k * Vn + lv];
      logits[lrow][lv] = a;
    }
    __syncthreads();

    // ---- log-softmax + CE (leader lanes; no barrier needed after: next write
    //      to `logits` is 2 barriers away, and leaders pass both only when done)
    if (tid < 16) {
      float mx = -3.4e38f;
#pragma unroll
      for (int v = 0; v < Vn; ++v) mx = fmaxf(mx, logits[tid][v]);
      float s = 0.f;
#pragma unroll
      for (int v = 0; v < Vn; ++v) s += fexp2((logits[tid][v] - mx) * 1.44269504f);
      int y = tok[tid][t + 1];
      float ce = (mx + __logf(s)) - logits[tid][y];
      ce_acc += ce * maskY[(row0 + tid) * Tn + t];
    }
  }

  if (tid < 16) red[tid] = ce_acc;
  __syncthreads();
  if (tid == 0) {
    float s = 0.f;
#pragma unroll
    for (int i = 0; i < 16; ++i) s += red[i];
    atomicAdd(ws + WS_LOSS, s);
  }
}

// K_final: out = loss_sum / mask_sum
__global__ void k_final(const float* __restrict__ ws, float* __restrict__ out) {
  if (threadIdx.x == 0 && blockIdx.x == 0) out[0] = ws[WS_LOSS] / ws[WS_MASK];
}

extern "C" void kernel_launch(void* const* d_in, const int* in_sizes, int n_in,
                              void* d_out, int out_size, void* d_ws, size_t ws_size,
                              hipStream_t stream) {
  const int*   inpt  = (const int*)  d_in[0];
  const float* h0    = (const float*)d_in[1];
  const float* c0    = (const float*)d_in[2];
  const float* maskY = (const float*)d_in[3];
  // d_in[4] = beta (unused by the reference computation)
  const float* emb   = (const float*)d_in[5];
  const float* W_ih  = (const float*)d_in[6];
  const float* b_ih  = (const float*)d_in[7];
  const float* W_hh  = (const float*)d_in[8];
  const float* b_hh  = (const float*)d_in[9];
  const float* W_lin = (const float*)d_in[10];
  const float* b_lin = (const float*)d_in[11];
  float* ws  = (float*)d_ws;
  float* out = (float*)d_out;

  hipLaunchKernelGGL(k_tlin,  dim3(1),   dim3(256), 0, stream, W_lin, ws);
  hipLaunchKernelGGL(k_xproj, dim3(60),  dim3(256), 0, stream, emb, W_ih, b_ih, b_hh, ws);
  hipLaunchKernelGGL(k_twhh,  dim3(64),  dim3(256), 0, stream, W_hh, ws);
  hipLaunchKernelGGL(k_mask,  dim3(128), dim3(256), 0, stream, maskY, ws);
  hipLaunchKernelGGL(k_main,  dim3(256), dim3(512), 0, stream, inpt, h0, c0, maskY, b_lin, ws);
  hipLaunchKernelGGL(k_final, dim3(1),   dim3(64),  0, stream, ws, out);
}

// Round 2
// 271.993 us; speedup vs baseline: 6.5232x; 6.5232x over previous
//
#include <hip/hip_runtime.h>

// DecoderLSTM: B=4096, T=128 (127 steps), H=128, 4H=512, V=30, E=256.
// MFMA version: gates = Xproj[tok] (exact fp32) + h @ W_hh^T via
// mfma_f32_16x16x32_bf16 (fp32 accum). W_hh fragments pre-swizzled and held
// in registers (64 VGPR/wave) for the entire 127-step loop. h double-buffered
// in LDS (bf16, padded row 136). Wave w owns N-tiles {w,8+w,16+w,24+w} so the
// pointwise cell runs in C-layout registers; c-state never leaves VGPRs.

typedef __bf16 bf16x8 __attribute__((ext_vector_type(8)));
typedef float  f32x4  __attribute__((ext_vector_type(4)));

namespace {
constexpr int Bn = 4096, Tn = 128, Vn = 30, En = 256, Hn = 128, Gn = 512;
constexpr int WS_LOSS  = 0;
constexpr int WS_MASK  = 1;
constexpr int WS_XPROJ = 16;                  // 30*512 fp32
constexpr int WS_WF_F  = WS_XPROJ + Vn * Gn;  // then: 65536 bf16 Whh-frags + 4096 bf16 Wlin-frags
}

__device__ __forceinline__ float fexp2(float x) { return __builtin_amdgcn_exp2f(x); }
__device__ __forceinline__ float frcp(float x)  { return __builtin_amdgcn_rcpf(x); }
__device__ __forceinline__ float sigf(float x)  { return frcp(1.f + fexp2(x * -1.44269504f)); }
__device__ __forceinline__ float tanh_(float x) { return 1.f - 2.f * frcp(fexp2(x * 2.88539008f) + 1.f); }

// ---- setup: W_hh -> B-fragment order (bf16). frag fid=((w*4+g)*4+kt)*64+l,
// element j = Whh^T[k][n] = W_hh[n][k], n=(g*8+w)*16+(l&15), k=kt*32+(l>>4)*8+j
__global__ void k_wfrag(const float* __restrict__ W_hh, float* __restrict__ ws) {
  int fid = blockIdx.x * 256 + threadIdx.x;  // 0..8191
  int l = fid & 63, kt = (fid >> 6) & 3, g = (fid >> 8) & 3, w = fid >> 10;
  int n  = (g * 8 + w) * 16 + (l & 15);
  int k0 = kt * 32 + (l >> 4) * 8;
  const float* src = W_hh + n * Hn + k0;
  union { __bf16 h[8]; uint4 u; } pk;
#pragma unroll
  for (int j = 0; j < 8; ++j) pk.h[j] = (__bf16)src[j];
  __bf16* wf = (__bf16*)(ws + WS_WF_F);
  *(uint4*)(wf + fid * 8) = pk.u;
}

// ---- setup: W_lin -> B-fragments (2 ntiles x 4 ktiles), + zero accumulators
__global__ void k_wlfrag(const float* __restrict__ W_lin, float* __restrict__ ws) {
  int fid = blockIdx.x * 256 + threadIdx.x;  // 0..511
  if (fid < 2) ws[fid] = 0.f;                // WS_LOSS, WS_MASK
  int l = fid & 63, kt = (fid >> 6) & 3, n = fid >> 8;
  int col = n * 16 + (l & 15);
  int k0  = kt * 32 + (l >> 4) * 8;
  union { __bf16 h[8]; uint4 u; } pk;
#pragma unroll
  for (int j = 0; j < 8; ++j)
    pk.h[j] = (col < Vn) ? (__bf16)W_lin[col * Hn + k0 + j] : (__bf16)0.f;
  __bf16* wf = (__bf16*)(ws + WS_WF_F);
  *(uint4*)(wf + 65536 + fid * 8) = pk.u;
}

// ---- setup: Xproj[v][j] = dot(emb[v], W_ih[j]) + b_ih[j] + b_hh[j]  (fp32 exact)
__global__ void k_xproj(const float* __restrict__ emb, const float* __restrict__ W_ih,
                        const float* __restrict__ b_ih, const float* __restrict__ b_hh,
                        float* __restrict__ ws) {
  __shared__ __align__(16) float es[En];
  int v = blockIdx.x >> 1;
  int j = ((blockIdx.x & 1) << 8) + threadIdx.x;
  es[threadIdx.x] = emb[v * En + threadIdx.x];
  __syncthreads();
  float a = b_ih[j] + b_hh[j];
  const float* wr = W_ih + j * En;
#pragma unroll 4
  for (int e = 0; e < En; e += 4) {
    float4 w = *(const float4*)(wr + e);
    float4 x = *(const float4*)(es + e);
    a += x.x * w.x + x.y * w.y + x.z * w.z + x.w * w.w;
  }
  ws[WS_XPROJ + v * Gn + j] = a;
}

// ---- setup: ws[WS_MASK] = sum(mask_Y)
__global__ void k_mask(const float* __restrict__ m, float* __restrict__ ws) {
  float s = 0.f;
  for (int i = blockIdx.x * 256 + threadIdx.x; i < Bn * Tn; i += 128 * 256) s += m[i];
#pragma unroll
  for (int off = 32; off > 0; off >>= 1) s += __shfl_down(s, off, 64);
  __shared__ float r[4];
  int lane = threadIdx.x & 63, w = threadIdx.x >> 6;
  if (lane == 0) r[w] = s;
  __syncthreads();
  if (threadIdx.x == 0) atomicAdd(ws + WS_MASK, r[0] + r[1] + r[2] + r[3]);
}

// ---- main: 256 blocks x 512 threads (8 waves), 16 batch rows/block, all steps
__global__ __launch_bounds__(512, 1) void k_main(
    const int* __restrict__ inpt, const float* __restrict__ h0,
    const float* __restrict__ c0, const float* __restrict__ maskY,
    const float* __restrict__ b_lin, float* __restrict__ ws) {
  __shared__ __align__(16) __bf16 hbuf[2][16][136];  // pad 136: <=2-way banks (free)
  __shared__ float logits[16][33];
  __shared__ int   tok[16][Tn];
  __shared__ float red[16];

  const float*  Xp  = ws + WS_XPROJ;
  const __bf16* wf  = (const __bf16*)(ws + WS_WF_F);
  const __bf16* wlf = wf + 65536;

  const int tid = threadIdx.x;
  const int w = tid >> 6, l = tid & 63, quad = l >> 4, lc = l & 15;
  const int row0 = blockIdx.x * 16;
  const int kh = w * 16 + lc;  // h-column this lane owns in pointwise / gate col base

  // W_hh B-fragments -> registers, held across the whole loop (64 VGPRs)
  bf16x8 wfr[4][4];
#pragma unroll
  for (int g = 0; g < 4; ++g)
#pragma unroll
    for (int kt = 0; kt < 4; ++kt)
      wfr[g][kt] = __builtin_bit_cast(
          bf16x8, *(const uint4*)(wf + (((w * 4 + g) * 4 + kt) * 64 + l) * 8));

  // W_lin B-fragments (waves 0,1 only) + b_lin broadcast
  bf16x8 wlr[4];
  if (w < 2) {
#pragma unroll
    for (int kt = 0; kt < 4; ++kt)
      wlr[kt] = __builtin_bit_cast(
          bf16x8, *(const uint4*)(wlf + ((w * 4 + kt) * 64 + l) * 8));
  }
  const float blv = (w < 2 && kh < Vn) ? b_lin[kh] : 0.f;

  for (int idx = tid; idx < 16 * Tn; idx += 512) {
    int r = idx >> 7, t = idx & 127;
    tok[r][t] = inpt[(row0 + r) * Tn + t];
  }
  for (int idx = tid; idx < 16 * Hn; idx += 512) {
    int r = idx >> 7, k = idx & 127;
    hbuf[0][r][k] = (__bf16)h0[(row0 + r) * Hn + k];
  }
  float creg[4];
#pragma unroll
  for (int p = 0; p < 4; ++p)
    creg[p] = c0[(row0 + quad * 4 + p) * Hn + kh];
  float ce_acc = 0.f;
  __syncthreads();

  int par = 0;
  for (int t = 0; t < Tn - 1; ++t) {
    const __bf16* hc = &hbuf[par][0][0];
    __bf16*       hn = &hbuf[par ^ 1][0][0];

    // A-fragments of h: row m=lc, k = kt*32 + quad*8 .. +8 (16B LDS reads)
    bf16x8 af[4];
#pragma unroll
    for (int kt = 0; kt < 4; ++kt)
      af[kt] = __builtin_bit_cast(
          bf16x8, *(const uint4*)(hc + lc * 136 + kt * 32 + quad * 8));

    // Xproj gather (fp32 exact, L2-hot), issued before the MFMA chain
    float xv[4][4];
#pragma unroll
    for (int p = 0; p < 4; ++p) {
      const float* xr = Xp + tok[quad * 4 + p][t] * Gn + kh;
#pragma unroll
      for (int g = 0; g < 4; ++g) xv[p][g] = xr[g * 128];
    }

    f32x4 acc[4] = {{0, 0, 0, 0}, {0, 0, 0, 0}, {0, 0, 0, 0}, {0, 0, 0, 0}};
#pragma unroll
    for (int g = 0; g < 4; ++g)
#pragma unroll
      for (int kt = 0; kt < 4; ++kt)
        acc[g] = __builtin_amdgcn_mfma_f32_16x16x32_bf16(af[kt], wfr[g][kt], acc[g], 0, 0, 0);

    // pointwise LSTM cell in C-layout registers: row=quad*4+p, col=kh
#pragma unroll
    for (int p = 0; p < 4; ++p) {
      float gi = acc[0][p] + xv[p][0];
      float gf = acc[1][p] + xv[p][1];
      float gg = acc[2][p] + xv[p][2];
      float go = acc[3][p] + xv[p][3];
      float c2 = sigf(gf) * creg[p] + sigf(gi) * tanh_(gg);
      float h2 = sigf(go) * tanh_(c2);
      creg[p] = c2;
      hn[(quad * 4 + p) * 136 + kh] = (__bf16)h2;
    }
    __syncthreads();  // B2: h(t+1) complete

    // logits: waves 0,1 -> ntile w (cols 0-15 / 16-31), K=128 via 4 MFMAs
    if (w < 2) {
      f32x4 lacc = {blv, blv, blv, blv};
#pragma unroll
      for (int kt = 0; kt < 4; ++kt) {
        bf16x8 a2 = __builtin_bit_cast(
            bf16x8, *(const uint4*)(hn + lc * 136 + kt * 32 + quad * 8));
        lacc = __builtin_amdgcn_mfma_f32_16x16x32_bf16(a2, wlr[kt], lacc, 0, 0, 0);
      }
      if (kh < Vn) {
#pragma unroll
        for (int p = 0; p < 4; ++p) logits[quad * 4 + p][kh] = lacc[p];
      }
    }
    __syncthreads();  // B3: logits complete

    // log-softmax + CE, 16 leader lanes (wave 0); others run ahead to t+1
    if (tid < 16) {
      float mx = -3.4e38f;
#pragma unroll
      for (int v = 0; v < Vn; ++v) mx = fmaxf(mx, logits[tid][v]);
      float s = 0.f;
#pragma unroll
      for (int v = 0; v < Vn; ++v) s += fexp2((logits[tid][v] - mx) * 1.44269504f);
      int y = tok[tid][t + 1];
      float ce = (mx + __logf(s)) - logits[tid][y];
      ce_acc += ce * maskY[(row0 + tid) * Tn + t];
    }
    par ^= 1;
  }

  if (tid < 16) red[tid] = ce_acc;
  __syncthreads();
  if (tid == 0) {
    float s = 0.f;
#pragma unroll
    for (int i = 0; i < 16; ++i) s += red[i];
    atomicAdd(ws + WS_LOSS, s);
  }
}

__global__ void k_final(const float* __restrict__ ws, float* __restrict__ out) {
  if (threadIdx.x == 0 && blockIdx.x == 0) out[0] = ws[WS_LOSS] / ws[WS_MASK];
}

extern "C" void kernel_launch(void* const* d_in, const int* in_sizes, int n_in,
                              void* d_out, int out_size, void* d_ws, size_t ws_size,
                              hipStream_t stream) {
  const int*   inpt  = (const int*)  d_in[0];
  const float* h0    = (const float*)d_in[1];
  const float* c0    = (const float*)d_in[2];
  const float* maskY = (const float*)d_in[3];
  // d_in[4] = beta (unused)
  const float* emb   = (const float*)d_in[5];
  const float* W_ih  = (const float*)d_in[6];
  const float* b_ih  = (const float*)d_in[7];
  const float* W_hh  = (const float*)d_in[8];
  const float* b_hh  = (const float*)d_in[9];
  const float* W_lin = (const float*)d_in[10];
  const float* b_lin = (const float*)d_in[11];
  float* ws  = (float*)d_ws;
  float* out = (float*)d_out;

  hipLaunchKernelGGL(k_wlfrag, dim3(2),   dim3(256), 0, stream, W_lin, ws);
  hipLaunchKernelGGL(k_wfrag,  dim3(32),  dim3(256), 0, stream, W_hh, ws);
  hipLaunchKernelGGL(k_xproj,  dim3(60),  dim3(256), 0, stream, emb, W_ih, b_ih, b_hh, ws);
  hipLaunchKernelGGL(k_mask,   dim3(128), dim3(256), 0, stream, maskY, ws);
  hipLaunchKernelGGL(k_main,   dim3(256), dim3(512), 0, stream, inpt, h0, c0, maskY, b_lin, ws);
  hipLaunchKernelGGL(k_final,  dim3(1),   dim3(64),  0, stream, ws, out);
}